// Round 8
// baseline (95.130 us; speedup 1.0000x reference)
//
#include <hip/hip_runtime.h>
#include <math.h>

#define WIN 7
#define W 4                    // windows per thread per tile
#define BLK 256
#define TILE (BLK * W)         // 1024 windows per tile
#define NB 2048                // grid for kmax_partial and kssim
#define NF4 ((TILE + 8) / 4)   // 258 float4 staged per array per tile
#define FIX_SCALE 274877906944.0   // 2^38 (Q38 fixed point; |sum| < 2^24 -> fits i64)

__device__ __forceinline__ float max4(float4 v) {
    return fmaxf(fmaxf(v.x, v.y), fmaxf(v.z, v.w));
}

// SSIM for one window from plain sums. Pre-scaled constants:
// c1=49*C1, c1d=2*c1, c2a=21*C2, c2b=42*C2.
__device__ __forceinline__ float ssim_win(float P, float Q, float sxx, float syy, float sxy,
                                          float c1, float c1d, float c2a, float c2b) {
    float t1 = P * Q;
    float u  = fmaf(P, P, Q * Q);
    float A1 = fmaf(t1, 4.0f, c1d);          // 2*(2PQ + 49C1)
    float A2 = fmaf(sxy, 7.0f, c2a - t1);    // 7sxy - PQ + 21C2
    float B1 = u + c1;
    float B2 = fmaf(sxx + syy, 7.0f, c2b - u);
    return (A1 * A2) * __builtin_amdgcn_rcpf(B1 * B2);
}

__device__ __forceinline__ float4 gload(const float* __restrict__ p, int f4, int n) {
    int f = f4 * 4;
    if (f + 4 <= n) return *(const float4*)(p + f);
    float4 v = {0.f, 0.f, 0.f, 0.f};
    if (f + 0 < n) v.x = p[f + 0];
    if (f + 1 < n) v.y = p[f + 1];
    if (f + 2 < n) v.z = p[f + 2];
    if (f + 3 < n) v.w = p[f + 3];
    return v;
}

__global__ __launch_bounds__(BLK) void kmax_partial(const float* __restrict__ y, int n,
                                                    float* __restrict__ outMax,
                                                    unsigned long long* __restrict__ accum,
                                                    unsigned int* __restrict__ counter) {
    if (blockIdx.x == 0 && threadIdx.x == 0) { *accum = 0ull; *counter = 0u; }
    const int gid = blockIdx.x * BLK + threadIdx.x;
    const int n4 = n >> 2;
    const int GS = NB * BLK;
    const float4* y4 = (const float4*)y;
    float m0 = -__builtin_huge_valf(), m1 = m0;
    int i = gid;
    for (; i + GS < n4; i += 2 * GS) {
        float4 a = y4[i];
        float4 b = y4[i + GS];
        m0 = fmaxf(m0, max4(a));
        m1 = fmaxf(m1, max4(b));
    }
    for (; i < n4; i += GS) m0 = fmaxf(m0, max4(y4[i]));
    for (int j = (n4 << 2) + gid; j < n; j += GS) m0 = fmaxf(m0, y[j]);
    float m = fmaxf(m0, m1);
    #pragma unroll
    for (int off = 32; off; off >>= 1) m = fmaxf(m, __shfl_xor(m, off));
    __shared__ float sm[4];
    if ((threadIdx.x & 63) == 0) sm[threadIdx.x >> 6] = m;
    __syncthreads();
    if (threadIdx.x == 0)
        outMax[blockIdx.x] = fmaxf(fmaxf(sm[0], sm[1]), fmaxf(sm[2], sm[3]));
}

__global__ __launch_bounds__(BLK) void kssim(const float* __restrict__ x,
                                             const float* __restrict__ y,
                                             const float* __restrict__ partMax, int n,
                                             int ntiles, int nw,
                                             unsigned long long* __restrict__ accum,
                                             unsigned int* __restrict__ counter,
                                             float* __restrict__ out) {
    const int tid = threadIdx.x;
    __shared__ float sm[4];
    __shared__ float4 lb[2][2][NF4];     // [buf][array(x=0,y=1)][float4 idx]

    // ---- block-local finalize of max(y) (8 KB, L2/L3-hot) ----
    float mm = -__builtin_huge_valf();
    #pragma unroll
    for (int i = 0; i < NB / BLK; i++) mm = fmaxf(mm, partMax[i * BLK + tid]);
    #pragma unroll
    for (int off = 32; off; off >>= 1) mm = fmaxf(mm, __shfl_xor(mm, off));
    if ((tid & 63) == 0) sm[tid >> 6] = mm;
    __syncthreads();
    const float dr = fmaxf(fmaxf(sm[0], sm[1]), fmaxf(sm[2], sm[3]));
    const float C1 = (0.01f * dr) * (0.01f * dr);
    const float C2 = (0.03f * dr) * (0.03f * dr);
    const float c1  = 49.0f * C1;
    const float c1d = 2.0f * c1;
    const float c2a = 21.0f * C2;
    const float c2b = 42.0f * C2;

    // ---- tiled, LDS-staged, double-buffered, 1 barrier per tile ----
    float acc = 0.0f;
    int tile = blockIdx.x;
    float4 ax0, ax1, ay0, ay1;           // staged regs for next tile (ax1/ay1: tid<2 only)
    if (tile < ntiles) {
        int b4 = tile * (TILE / 4);
        ax0 = gload(x, b4 + tid, n);
        ay0 = gload(y, b4 + tid, n);
        if (tid < NF4 - BLK) {
            ax1 = gload(x, b4 + BLK + tid, n);
            ay1 = gload(y, b4 + BLK + tid, n);
        }
    }
    int it = 0;
    for (; tile < ntiles; tile += NB, ++it) {
        const int buf = it & 1;
        lb[buf][0][tid] = ax0;
        lb[buf][1][tid] = ay0;
        if (tid < NF4 - BLK) {
            lb[buf][0][BLK + tid] = ax1;
            lb[buf][1][BLK + tid] = ay1;
        }
        const int ntile = tile + NB;
        if (ntile < ntiles) {            // prefetch next tile before the barrier
            int b4 = ntile * (TILE / 4);
            ax0 = gload(x, b4 + tid, n);
            ay0 = gload(y, b4 + tid, n);
            if (tid < NF4 - BLK) {
                ax1 = gload(x, b4 + BLK + tid, n);
                ay1 = gload(y, b4 + BLK + tid, n);
            }
        }
        __syncthreads();                 // lb[buf] visible; prev reads of lb[buf] done 2 iters ago

        const float* lx = (const float*)&lb[buf][0][0];
        const float* ly = (const float*)&lb[buf][1][0];
        float4 f0 = *(const float4*)(lx + 4 * tid);
        float4 f1 = *(const float4*)(lx + 4 * tid + 4);
        float4 f2 = *(const float4*)(lx + 4 * tid + 8);
        float4 g0 = *(const float4*)(ly + 4 * tid);
        float4 g1 = *(const float4*)(ly + 4 * tid + 4);
        float4 g2 = *(const float4*)(ly + 4 * tid + 8);
        float xv[12] = {f0.x,f0.y,f0.z,f0.w, f1.x,f1.y,f1.z,f1.w, f2.x,f2.y,f2.z,f2.w};
        float yv[12] = {g0.x,g0.y,g0.z,g0.w, g1.x,g1.y,g1.z,g1.w, g2.x,g2.y,g2.z,g2.w};

        float P = 0.f, Q = 0.f, sxx = 0.f, syy = 0.f, sxy = 0.f;
        #pragma unroll
        for (int k = 0; k < WIN; k++) {
            float a = xv[k], b = yv[k];
            P += a; Q += b;
            sxx = fmaf(a, a, sxx);
            syy = fmaf(b, b, syy);
            sxy = fmaf(a, b, sxy);
        }
        const int T = tile * TILE;
        if (T + TILE + 8 <= n) {         // full tile: no per-window guards
            #pragma unroll
            for (int j = 0; j < W; j++) {
                acc += ssim_win(P, Q, sxx, syy, sxy, c1, c1d, c2a, c2b);
                if (j < W - 1) {
                    float ao = xv[j], an = xv[j + WIN];
                    float bo = yv[j], bn = yv[j + WIN];
                    P += an - ao;
                    Q += bn - bo;
                    sxx += fmaf(an, an, -(ao * ao));
                    syy += fmaf(bn, bn, -(bo * bo));
                    sxy += fmaf(an, bn, -(ao * bo));
                }
            }
        } else {                         // last tile: guard each window
            const int w0 = T + 4 * tid;
            #pragma unroll
            for (int j = 0; j < W; j++) {
                if (w0 + j < nw)
                    acc += ssim_win(P, Q, sxx, syy, sxy, c1, c1d, c2a, c2b);
                if (j < W - 1) {
                    float ao = xv[j], an = xv[j + WIN];
                    float bo = yv[j], bn = yv[j + WIN];
                    P += an - ao;
                    Q += bn - bo;
                    sxx += fmaf(an, an, -(ao * ao));
                    syy += fmaf(bn, bn, -(bo * bo));
                    sxy += fmaf(an, bn, -(ao * bo));
                }
            }
        }
    }

    // ---- block reduce + deterministic fixed-point global accumulate ----
    #pragma unroll
    for (int off = 32; off; off >>= 1) acc += __shfl_xor(acc, off);
    __syncthreads();                     // sm reuse
    if ((tid & 63) == 0) sm[tid >> 6] = acc;
    __syncthreads();
    if (tid == 0) {
        float bs = (sm[0] + sm[1]) + (sm[2] + sm[3]);
        long long q = (long long)rint((double)bs * FIX_SCALE);
        atomicAdd(accum, (unsigned long long)q);
        __threadfence();
        unsigned int prev = atomicAdd(counter, 1u);
        if (prev == (unsigned int)(gridDim.x - 1)) {   // last block finalizes
            unsigned long long tot = atomicAdd(accum, 0ull);
            double s = (double)(long long)tot / FIX_SCALE;
            out[0] = (float)(s / (double)nw);
        }
    }
}

extern "C" void kernel_launch(void* const* d_in, const int* in_sizes, int n_in,
                              void* d_out, int out_size, void* d_ws, size_t ws_size,
                              hipStream_t stream) {
    const float* x = (const float*)d_in[0];
    const float* y = (const float*)d_in[1];
    float* out = (float*)d_out;
    int n = in_sizes[0];
    int nw = n - (WIN - 1);
    int ntiles = (nw + TILE - 1) / TILE;

    unsigned long long* accum = (unsigned long long*)d_ws;        // 8 B
    unsigned int* counter = (unsigned int*)((char*)d_ws + 8);     // 4 B
    float* partMax = (float*)((char*)d_ws + 256);                 // NB floats

    kmax_partial<<<NB, BLK, 0, stream>>>(y, n, partMax, accum, counter);
    kssim<<<NB, BLK, 0, stream>>>(x, y, partMax, n, ntiles, nw, accum, counter, out);
}